// Round 2
// baseline (441.469 us; speedup 1.0000x reference)
//
#include <hip/hip_runtime.h>
#include <math.h>

#define BN_EPS_F 1e-5f

// ---------------------------------------------------------------------------
// Layer 1: K=8 — memory-bound, one thread per 4 outputs.
// h1[m][n] = relu(bn(dot(G[m,:8], W1[n,:8]) + b1))
// ---------------------------------------------------------------------------
__global__ __launch_bounds__(256)
void l1_kernel(const float* __restrict__ G, const float* __restrict__ W1,
               const float* __restrict__ bias, const float* __restrict__ gamma,
               const float* __restrict__ beta, const float* __restrict__ mean,
               const float* __restrict__ var, float* __restrict__ h1)
{
    const int m = blockIdx.x;
    const int t = threadIdx.x;
    if (t >= 250) return;
    const int n = 4 * t;

    float4 g0 = *(const float4*)(G + (size_t)m * 8 + 0);
    float4 g1 = *(const float4*)(G + (size_t)m * 8 + 4);

    float4 bi = *(const float4*)(bias + n);
    float4 ga = *(const float4*)(gamma + n);
    float4 be = *(const float4*)(beta + n);
    float4 mu = *(const float4*)(mean + n);
    float4 va = *(const float4*)(var + n);

    float4 out;
    float* op = &out.x;
    const float* bip = &bi.x; const float* gap = &ga.x; const float* bep = &be.x;
    const float* mup = &mu.x; const float* vap = &va.x;
#pragma unroll
    for (int j = 0; j < 4; ++j) {
        const float* w = W1 + (size_t)(n + j) * 8;
        float4 w0 = *(const float4*)(w + 0);
        float4 w1 = *(const float4*)(w + 4);
        float d = g0.x*w0.x + g0.y*w0.y + g0.z*w0.z + g0.w*w0.w
                + g1.x*w1.x + g1.y*w1.y + g1.z*w1.z + g1.w*w1.w;
        float s  = gap[j] * rsqrtf(vap[j] + BN_EPS_F);
        float t0 = fmaf(s, bip[j] - mup[j], bep[j]);
        op[j] = fmaxf(fmaf(s, d, t0), 0.f);
    }
    *(float4*)(h1 + (size_t)m * 1000 + n) = out;
}

// ---------------------------------------------------------------------------
// Tiled fp32 GEMM:  C = act(s*(A @ B^T) + t)  (or raw partial for split-K)
// 256 threads = 4 waves (2x2), wave = 8x8 lanes, lane tile 4x4 -> block 64x64.
// All LDS fragment reads are ds_read_b128 with 8-way broadcast (conflict-free).
// Double-buffered LDS, BK=32, reg-staged global prefetch.
// MODE 0: BN+relu, MODE 1: BN+sigmoid, MODE 2: raw partial store.
// blockIdx.z = split-K index, k-range [z*kchunk, min(K,(z+1)*kchunk)).
// ---------------------------------------------------------------------------
template<int MODE>
__global__ __launch_bounds__(256, 2)
void gemm64(const float* __restrict__ A, int M, int K, int lda,
            const float* __restrict__ B, int N, int ldb,
            int kchunk,
            const float* __restrict__ bias, const float* __restrict__ gamma,
            const float* __restrict__ beta, const float* __restrict__ mean,
            const float* __restrict__ var,
            float* __restrict__ C, int ldc, size_t pstride)
{
    __shared__ float As[2][32][68];
    __shared__ float Bs[2][32][68];

    const int tid  = threadIdx.x;
    const int w    = tid >> 6, lane = tid & 63;
    const int wx   = w & 1,  wy = w >> 1;
    const int tx   = lane & 7, ty = lane >> 3;
    const int m0   = blockIdx.y * 64;
    const int n0   = blockIdx.x * 64;
    const int z    = blockIdx.z;
    const int ks   = z * kchunk;
    const int ke   = min(K, ks + kchunk);

    // staging geometry: slot = tid (+256); row = slot>>3 (0..31, +32), kq = slot&7
    const int srow = tid >> 3;
    const int skq  = tid & 7;
    const float* Ar0 = A + (size_t)(m0 + srow)      * lda;
    const float* Ar1 = A + (size_t)(m0 + srow + 32) * lda;
    const float* Br0 = B + (size_t)(n0 + srow)      * ldb;
    const float* Br1 = B + (size_t)(n0 + srow + 32) * ldb;
    const bool bv0 = (n0 + srow)      < N;
    const bool bv1 = (n0 + srow + 32) < N;

    float4 pa0, pa1, pb0, pb1;
    const float4 zf4 = make_float4(0.f, 0.f, 0.f, 0.f);

    auto gload = [&](int kt) {
        const int kg = kt + 4 * skq;
        const bool kv = kg < ke;           // ke%4==0 everywhere -> all-or-none
        pa0 = kv        ? *(const float4*)(Ar0 + kg) : zf4;
        pa1 = kv        ? *(const float4*)(Ar1 + kg) : zf4;
        pb0 = (kv&&bv0) ? *(const float4*)(Br0 + kg) : zf4;
        pb1 = (kv&&bv1) ? *(const float4*)(Br1 + kg) : zf4;
    };
    auto lwrite = [&](int buf) {
        As[buf][4*skq+0][srow]    = pa0.x; As[buf][4*skq+1][srow]    = pa0.y;
        As[buf][4*skq+2][srow]    = pa0.z; As[buf][4*skq+3][srow]    = pa0.w;
        As[buf][4*skq+0][srow+32] = pa1.x; As[buf][4*skq+1][srow+32] = pa1.y;
        As[buf][4*skq+2][srow+32] = pa1.z; As[buf][4*skq+3][srow+32] = pa1.w;
        Bs[buf][4*skq+0][srow]    = pb0.x; Bs[buf][4*skq+1][srow]    = pb0.y;
        Bs[buf][4*skq+2][srow]    = pb0.z; Bs[buf][4*skq+3][srow]    = pb0.w;
        Bs[buf][4*skq+0][srow+32] = pb1.x; Bs[buf][4*skq+1][srow+32] = pb1.y;
        Bs[buf][4*skq+2][srow+32] = pb1.z; Bs[buf][4*skq+3][srow+32] = pb1.w;
    };

    float acc[4][4];
#pragma unroll
    for (int i = 0; i < 4; ++i)
#pragma unroll
        for (int j = 0; j < 4; ++j) acc[i][j] = 0.f;

    const int nt = (ke - ks + 31) / 32;
    gload(ks);
    lwrite(0);
    __syncthreads();

    const int ar = wy * 32 + ty * 4;
    const int br = wx * 32 + tx * 4;

    for (int t = 0; t < nt; ++t) {
        const int cur = t & 1;
        if (t + 1 < nt) gload(ks + (t + 1) * 32);
#pragma unroll
        for (int kk = 0; kk < 32; ++kk) {
            float4 a = *(const float4*)&As[cur][kk][ar];
            float4 b = *(const float4*)&Bs[cur][kk][br];
            acc[0][0] = fmaf(a.x, b.x, acc[0][0]);
            acc[0][1] = fmaf(a.x, b.y, acc[0][1]);
            acc[0][2] = fmaf(a.x, b.z, acc[0][2]);
            acc[0][3] = fmaf(a.x, b.w, acc[0][3]);
            acc[1][0] = fmaf(a.y, b.x, acc[1][0]);
            acc[1][1] = fmaf(a.y, b.y, acc[1][1]);
            acc[1][2] = fmaf(a.y, b.z, acc[1][2]);
            acc[1][3] = fmaf(a.y, b.w, acc[1][3]);
            acc[2][0] = fmaf(a.z, b.x, acc[2][0]);
            acc[2][1] = fmaf(a.z, b.y, acc[2][1]);
            acc[2][2] = fmaf(a.z, b.z, acc[2][2]);
            acc[2][3] = fmaf(a.z, b.w, acc[2][3]);
            acc[3][0] = fmaf(a.w, b.x, acc[3][0]);
            acc[3][1] = fmaf(a.w, b.y, acc[3][1]);
            acc[3][2] = fmaf(a.w, b.z, acc[3][2]);
            acc[3][3] = fmaf(a.w, b.w, acc[3][3]);
        }
        __syncthreads();
        if (t + 1 < nt) {
            lwrite(cur ^ 1);
            __syncthreads();
        }
    }

    // ---- epilogue ----
    const int col = n0 + br;
    const int row = m0 + ar;
    if (col < N) {   // N%4==0 -> whole float4 in range
        if (MODE == 2) {
            float* Cz = C + z * pstride;
#pragma unroll
            for (int i = 0; i < 4; ++i) {
                float4 v = make_float4(acc[i][0], acc[i][1], acc[i][2], acc[i][3]);
                *(float4*)(Cz + (size_t)(row + i) * ldc + col) = v;
            }
        } else {
            float4 ga = *(const float4*)(gamma + col);
            float4 va = *(const float4*)(var + col);
            float4 bi = *(const float4*)(bias + col);
            float4 mu = *(const float4*)(mean + col);
            float4 be = *(const float4*)(beta + col);
            float s0 = ga.x * rsqrtf(va.x + BN_EPS_F);
            float s1 = ga.y * rsqrtf(va.y + BN_EPS_F);
            float s2 = ga.z * rsqrtf(va.z + BN_EPS_F);
            float s3 = ga.w * rsqrtf(va.w + BN_EPS_F);
            float t0 = fmaf(s0, bi.x - mu.x, be.x);
            float t1 = fmaf(s1, bi.y - mu.y, be.y);
            float t2 = fmaf(s2, bi.z - mu.z, be.z);
            float t3 = fmaf(s3, bi.w - mu.w, be.w);
#pragma unroll
            for (int i = 0; i < 4; ++i) {
                float y0 = fmaf(s0, acc[i][0], t0);
                float y1 = fmaf(s1, acc[i][1], t1);
                float y2 = fmaf(s2, acc[i][2], t2);
                float y3 = fmaf(s3, acc[i][3], t3);
                if (MODE == 0) {
                    y0 = fmaxf(y0, 0.f); y1 = fmaxf(y1, 0.f);
                    y2 = fmaxf(y2, 0.f); y3 = fmaxf(y3, 0.f);
                } else {
                    y0 = 1.f/(1.f+expf(-y0)); y1 = 1.f/(1.f+expf(-y1));
                    y2 = 1.f/(1.f+expf(-y2)); y3 = 1.f/(1.f+expf(-y3));
                }
                *(float4*)(C + (size_t)(row + i) * ldc + col) =
                    make_float4(y0, y1, y2, y3);
            }
        }
    }
}

// ---------------------------------------------------------------------------
// Split-K reduce for layer 3 + BN + sigmoid -> p (2048 x 300, stride 300)
// ---------------------------------------------------------------------------
__global__ __launch_bounds__(256)
void reduce3_sigmoid(const float* __restrict__ part, size_t pstride,
                     const float* __restrict__ bias, const float* __restrict__ gamma,
                     const float* __restrict__ beta, const float* __restrict__ mean,
                     const float* __restrict__ var, float* __restrict__ p)
{
    const int i = blockIdx.x * 256 + threadIdx.x;   // one float4 each
    if (i >= 2048 * 75) return;
    const int m = i / 75;
    const int n = (i % 75) * 4;
    const size_t off = (size_t)m * 304 + n;
    float4 v0 = *(const float4*)(part + off);
    float4 v1 = *(const float4*)(part + pstride + off);
    float4 v2 = *(const float4*)(part + 2 * pstride + off);
    float4 ga = *(const float4*)(gamma + n);
    float4 va = *(const float4*)(var + n);
    float4 bi = *(const float4*)(bias + n);
    float4 mu = *(const float4*)(mean + n);
    float4 be = *(const float4*)(beta + n);
    float4 out;
    float d0 = v0.x + v1.x + v2.x, d1 = v0.y + v1.y + v2.y;
    float d2 = v0.z + v1.z + v2.z, d3 = v0.w + v1.w + v2.w;
    float s0 = ga.x * rsqrtf(va.x + BN_EPS_F), s1 = ga.y * rsqrtf(va.y + BN_EPS_F);
    float s2 = ga.z * rsqrtf(va.z + BN_EPS_F), s3 = ga.w * rsqrtf(va.w + BN_EPS_F);
    out.x = 1.f/(1.f+expf(-(fmaf(s0, d0 + bi.x - mu.x, be.x))));
    out.y = 1.f/(1.f+expf(-(fmaf(s1, d1 + bi.y - mu.y, be.y))));
    out.z = 1.f/(1.f+expf(-(fmaf(s2, d2 + bi.z - mu.z, be.z))));
    out.w = 1.f/(1.f+expf(-(fmaf(s3, d3 + bi.w - mu.w, be.w))));
    *(float4*)(p + (size_t)m * 300 + n) = out;
}

// ---------------------------------------------------------------------------
// Lorentz spectrum: one block per batch row, 100 oscillators in LDS,
// 300 spectral points across 300 threads.
// ---------------------------------------------------------------------------
__global__ __launch_bounds__(320)
void lorentz_kernel(const float* __restrict__ P,     // 2048 x 300
                    const float* __restrict__ G,     // 2048 x 8
                    const float* __restrict__ wgrid, // 300
                    float* __restrict__ T)           // 2048 x 300
{
    __shared__ float s_w02[100], s_wp2[100], s_wp2g[100], s_g2[100];
    const int b   = blockIdx.x;
    const int tid = threadIdx.x;
    if (tid < 100) {
        const float* p = P + (size_t)b*300 + 3*tid;
        const float w0 = p[0]*5.f;
        const float wp = p[1]*5.f;
        const float g  = p[2]*0.5f;
        s_w02[tid]  = w0*w0;
        s_wp2[tid]  = wp*wp;
        s_g2[tid]   = g*g;
        s_wp2g[tid] = wp*wp*g;
    }
    __syncthreads();
    if (tid < 300) {
        const float wg = wgrid[tid];
        const float w2 = wg*wg;
        float e1 = 0.f, e2s = 0.f;
#pragma unroll 10
        for (int l = 0; l < 100; ++l) {
            const float s1    = s_w02[l] - w2;
            const float denom = fmaf(s1, s1, w2 * s_g2[l]);
            const float r     = __builtin_amdgcn_rcpf(denom);
            e1  = fmaf(s_wp2[l]*s1, r, e1);
            e2s = fmaf(s_wp2g[l],   r, e2s);
        }
        e1 += 10.f;
        const float e2  = e2s * wg;
        const float mag = sqrtf(fmaf(e1, e1, e2*e2));
        const float nn  = sqrtf(0.5f*(mag + e1));
        const float kk  = sqrtf(fmaxf(0.5f*(mag - e1), 0.f));
        const float d   = fmaxf(fmaxf(G[b*8+4], G[b*8+5]),
                                fmaxf(G[b*8+6], G[b*8+7]));
        const float ab  = expf(-0.006283185307179586f * d * kk);
        const float np1 = nn + 1.f;
        const float Tv  = 4.f*nn / fmaf(np1, np1, kk*kk) * ab;
        T[(size_t)b*300 + tid] = Tv;
    }
}

extern "C" void kernel_launch(void* const* d_in, const int* in_sizes, int n_in,
                              void* d_out, int out_size, void* d_ws, size_t ws_size,
                              hipStream_t stream) {
    const float* G      = (const float*)d_in[0];
    const float* W1     = (const float*)d_in[1];
    const float* b1     = (const float*)d_in[2];
    const float* gamma1 = (const float*)d_in[3];
    const float* beta1  = (const float*)d_in[4];
    const float* mean1  = (const float*)d_in[5];
    const float* var1   = (const float*)d_in[6];
    const float* W2     = (const float*)d_in[7];
    const float* b2     = (const float*)d_in[8];
    const float* gamma2 = (const float*)d_in[9];
    const float* beta2  = (const float*)d_in[10];
    const float* mean2  = (const float*)d_in[11];
    const float* var2   = (const float*)d_in[12];
    const float* W3     = (const float*)d_in[13];
    const float* b3     = (const float*)d_in[14];
    const float* gamma3 = (const float*)d_in[15];
    const float* beta3  = (const float*)d_in[16];
    const float* mean3  = (const float*)d_in[17];
    const float* var3   = (const float*)d_in[18];
    const float* wgrid  = (const float*)d_in[19];

    float* ws   = (float*)d_ws;
    float* h1   = ws;                        // 2048*1000 floats (later reused as L3 partials)
    float* h2   = ws + 2048 * 1000;          // 2048*1000 floats
    float* p    = ws + 2 * 2048 * 1000;      // 2048*300 floats
    float* part = h1;                        // L3 partials alias h1 (dead after L2)
    const size_t pstride = (size_t)2048 * 304;   // 3 * this = 1.87M floats <= h1 region
    float* T = (float*)d_out;

    // Layer 1 (K=8, memory-bound)
    l1_kernel<<<2048, 256, 0, stream>>>(G, W1, b1, gamma1, beta1, mean1, var1, h1);

    // Layer 2: 2048x1000, K=1000 -> h2   (grid 16n x 32m = 512 blocks)
    gemm64<0><<<dim3(16, 32, 1), 256, 0, stream>>>(
        h1, 2048, 1000, 1000, W2, 1000, 1000, 1000,
        b2, gamma2, beta2, mean2, var2, h2, 1000, 0);

    // Layer 3: 2048x300, K=1000, split-K=3 -> partials (grid 5 x 32 x 3)
    gemm64<2><<<dim3(5, 32, 3), 256, 0, stream>>>(
        h2, 2048, 1000, 1000, W3, 300, 1000, 336,
        nullptr, nullptr, nullptr, nullptr, nullptr, part, 304, pstride);

    // Reduce partials + BN + sigmoid -> p
    reduce3_sigmoid<<<600, 256, 0, stream>>>(part, pstride,
        b3, gamma3, beta3, mean3, var3, p);

    // Lorentz spectrum -> T
    lorentz_kernel<<<2048, 320, 0, stream>>>(p, G, wgrid, T);
}